// Round 2
// baseline (582.838 us; speedup 1.0000x reference)
//
#include <hip/hip_runtime.h>
#include <hip/hip_bf16.h>

#define PAD 68
#define SCALE 0.35355339059327379f

__device__ __forceinline__ void fma16(float acc[16], float a, const float* b) {
    const float4* b4 = reinterpret_cast<const float4*>(b);
    float4 x0 = b4[0], x1 = b4[1], x2 = b4[2], x3 = b4[3];
    acc[0]  += a * x0.x; acc[1]  += a * x0.y; acc[2]  += a * x0.z; acc[3]  += a * x0.w;
    acc[4]  += a * x1.x; acc[5]  += a * x1.y; acc[6]  += a * x1.z; acc[7]  += a * x1.w;
    acc[8]  += a * x2.x; acc[9]  += a * x2.y; acc[10] += a * x2.z; acc[11] += a * x2.w;
    acc[12] += a * x3.x; acc[13] += a * x3.y; acc[14] += a * x3.z; acc[15] += a * x3.w;
}

// ---------- A: landmark pooling (Q,K -> Qlm,Klm, pre-scaled by SCALE/64) ----------
__global__ __launch_bounds__(256) void pool_kernel(const float* __restrict__ Q,
                                                   const float* __restrict__ K,
                                                   float* __restrict__ Qlm,
                                                   float* __restrict__ Klm) {
    __shared__ float4 red[256];
    const int blk = blockIdx.x;          // bh*64 + landmark
    const int t = threadIdx.x;
    const int d4 = t & 15;               // 16 dim-groups of 4
    const int rg = t >> 4;               // 16 row-groups of 4 rows
    const float4* Q4 = reinterpret_cast<const float4*>(Q);
    const float4* K4 = reinterpret_cast<const float4*>(K);

    float4 sQ = {0.f, 0.f, 0.f, 0.f}, sK = {0.f, 0.f, 0.f, 0.f};
#pragma unroll
    for (int rr = 0; rr < 4; rr++) {
        int row = blk * 64 + rg * 4 + rr;
        int off4 = (row << 4) + d4;
        float4 q = Q4[off4], k = K4[off4];
        sQ.x += q.x; sQ.y += q.y; sQ.z += q.z; sQ.w += q.w;
        sK.x += k.x; sK.y += k.y; sK.z += k.z; sK.w += k.w;
    }
    const float c = SCALE * (1.0f / 64.0f);
    red[t] = sQ;
    __syncthreads();
    if (t < 16) {
        float4 s = {0.f, 0.f, 0.f, 0.f};
#pragma unroll
        for (int g = 0; g < 16; g++) {
            float4 v = red[g * 16 + t];
            s.x += v.x; s.y += v.y; s.z += v.z; s.w += v.w;
        }
        s.x *= c; s.y *= c; s.z *= c; s.w *= c;
        reinterpret_cast<float4*>(Qlm + blk * 64)[t] = s;
    }
    __syncthreads();
    red[t] = sK;
    __syncthreads();
    if (t < 16) {
        float4 s = {0.f, 0.f, 0.f, 0.f};
#pragma unroll
        for (int g = 0; g < 16; g++) {
            float4 v = red[g * 16 + t];
            s.x += v.x; s.y += v.y; s.z += v.z; s.w += v.w;
        }
        s.x *= c; s.y *= c; s.z *= c; s.w *= c;
        reinterpret_cast<float4*>(Klm + blk * 64)[t] = s;
    }
}

// ---------- B: K2 = softmax(Qlm Klm^T), global col-sum max ----------
__global__ __launch_bounds__(256) void k2_kernel(const float* __restrict__ Qlm,
                                                 const float* __restrict__ Klm,
                                                 float* __restrict__ K2g,
                                                 unsigned* __restrict__ colmax) {
    __shared__ float Ql[64 * PAD], Kl[64 * PAD], S2[64 * PAD];
    const int bh = blockIdx.x, t = threadIdx.x;
#pragma unroll
    for (int n = 0; n < 16; n++) {
        int f = t + n * 256;
        Ql[(f >> 6) * PAD + (f & 63)] = Qlm[bh * 4096 + f];
        Kl[(f >> 6) * PAD + (f & 63)] = Klm[bh * 4096 + f];
    }
    __syncthreads();
    const int i = t >> 2, j0 = (t & 3) * 16;
    float acc[16];
#pragma unroll
    for (int u = 0; u < 16; u++) acc[u] = 0.f;
    const float4* Ql4 = reinterpret_cast<const float4*>(Ql);
    const float4* Kl4 = reinterpret_cast<const float4*>(Kl);
    for (int k4 = 0; k4 < 16; k4++) {
        float4 a = Ql4[i * 17 + k4];
#pragma unroll
        for (int u = 0; u < 16; u++) {
            float4 b = Kl4[(j0 + u) * 17 + k4];
            acc[u] += a.x * b.x + a.y * b.y + a.z * b.z + a.w * b.w;
        }
    }
#pragma unroll
    for (int u = 0; u < 16; u++) S2[i * PAD + j0 + u] = acc[u];
    __syncthreads();
    if (t < 64) {  // row softmax
        float m = -1e30f;
        for (int j = 0; j < 64; j++) m = fmaxf(m, S2[t * PAD + j]);
        float sum = 0.f;
        for (int j = 0; j < 64; j++) {
            float e = __expf(S2[t * PAD + j] - m);
            S2[t * PAD + j] = e; sum += e;
        }
        float inv = 1.0f / sum;
        for (int j = 0; j < 64; j++) S2[t * PAD + j] *= inv;
    }
    __syncthreads();
#pragma unroll
    for (int n = 0; n < 16; n++) {
        int f = t + n * 256;
        K2g[bh * 4096 + f] = S2[(f >> 6) * PAD + (f & 63)];
    }
    if (t < 64) {
        float c = 0.f;
        for (int ii = 0; ii < 64; ii++) c += S2[ii * PAD + t];
        atomicMax(colmax, __float_as_uint(c));   // positive floats: uint order == float order
    }
}

// ---------- C: Newton-Schulz inverse (6 iters) ----------
__global__ __launch_bounds__(256) void inv_kernel(const float* __restrict__ K2g,
                                                  const unsigned* __restrict__ colmax,
                                                  float* __restrict__ K2invg) {
    __shared__ float Vb[64 * PAD], Ab[64 * PAD], Tb[64 * PAD];
    const int bh = blockIdx.x, t = threadIdx.x;
    const float sc = 1.0f / __uint_as_float(*colmax);   // rowmax == 1 (softmax rows)
    const float* Kg = K2g + bh * 4096;
#pragma unroll
    for (int n = 0; n < 16; n++) {
        int f = t + n * 256;
        Vb[(f >> 6) * PAD + (f & 63)] = sc * Kg[(f & 63) * 64 + (f >> 6)];  // V0 = sc*K^T
    }
    __syncthreads();
    const int i = t >> 2, j0 = (t & 3) * 16;
    for (int iter = 0; iter < 6; iter++) {
        float acc[16], vacc[16];
        // A = K @ V
#pragma unroll
        for (int u = 0; u < 16; u++) acc[u] = 0.f;
        for (int k = 0; k < 64; k++) fma16(acc, Kg[i * 64 + k], Vb + k * PAD + j0);
#pragma unroll
        for (int u = 0; u < 16; u++) Ab[i * PAD + j0 + u] = acc[u];
        __syncthreads();
        // T1 = V@A ; vacc = 13V - 15*T1
#pragma unroll
        for (int u = 0; u < 16; u++) acc[u] = 0.f;
        for (int k = 0; k < 64; k++) fma16(acc, Vb[i * PAD + k], Ab + k * PAD + j0);
#pragma unroll
        for (int u = 0; u < 16; u++) {
            vacc[u] = 13.f * Vb[i * PAD + j0 + u] - 15.f * acc[u];
            Tb[i * PAD + j0 + u] = acc[u];
        }
        __syncthreads();
        // T2 = T1@A (stored into V) ; vacc += 7*T2
#pragma unroll
        for (int u = 0; u < 16; u++) acc[u] = 0.f;
        for (int k = 0; k < 64; k++) fma16(acc, Tb[i * PAD + k], Ab + k * PAD + j0);
#pragma unroll
        for (int u = 0; u < 16; u++) { vacc[u] += 7.f * acc[u]; Vb[i * PAD + j0 + u] = acc[u]; }
        __syncthreads();
        // T3 = T2@A (registers only) ; vacc -= T3
#pragma unroll
        for (int u = 0; u < 16; u++) acc[u] = 0.f;
        for (int k = 0; k < 64; k++) fma16(acc, Vb[i * PAD + k], Ab + k * PAD + j0);
#pragma unroll
        for (int u = 0; u < 16; u++) vacc[u] -= acc[u];
        __syncthreads();
        // V = 0.25 * vacc
#pragma unroll
        for (int u = 0; u < 16; u++) Vb[i * PAD + j0 + u] = 0.25f * vacc[u];
        __syncthreads();
    }
#pragma unroll
    for (int n = 0; n < 16; n++) {
        int f = t + n * 256;
        K2invg[bh * 4096 + f] = Vb[(f >> 6) * PAD + (f & 63)];
    }
}

// ---------- D: W2acc += exp(Qlm (SCALE*K)^T) @ V ; rowsum3 += exp-sums ----------
__global__ __launch_bounds__(256) void k3v_kernel(const float* __restrict__ Qlm,
                                                  const float* __restrict__ K,
                                                  const float* __restrict__ V,
                                                  float* __restrict__ W2acc,
                                                  float* __restrict__ rowsum3) {
    __shared__ float Qs[64 * PAD];
    __shared__ float KT[64 * PAD];   // doubles as E after logits
    __shared__ float Vt[64 * PAD];
    const int chunk = blockIdx.x, bh = blockIdx.y, t = threadIdx.x;
    const float4* K4 = reinterpret_cast<const float4*>(K);
    const float4* V4 = reinterpret_cast<const float4*>(V);
#pragma unroll
    for (int n = 0; n < 16; n++) {
        int f = t + n * 256;
        Qs[(f >> 6) * PAD + (f & 63)] = Qlm[bh * 4096 + f];
    }
    const int i = t >> 2, j0 = (t & 3) * 16;
    float acc[16];
#pragma unroll
    for (int u = 0; u < 16; u++) acc[u] = 0.f;
    float rsum = 0.f;
    __syncthreads();

    for (int tile = 0; tile < 8; tile++) {
        const int sb = chunk * 512 + tile * 64;
        // stage K (transposed, pre-scaled) and V (row-major)
#pragma unroll
        for (int n = 0; n < 4; n++) {
            int f4 = t + n * 256;            // 0..1023 float4s
            int s = f4 >> 4, k0 = (f4 & 15) * 4;
            int gidx4 = (bh * 4096 + sb + s) * 16 + (f4 & 15);
            float4 k = K4[gidx4];
            float4 v = V4[gidx4];
            KT[(k0 + 0) * PAD + s] = SCALE * k.x;
            KT[(k0 + 1) * PAD + s] = SCALE * k.y;
            KT[(k0 + 2) * PAD + s] = SCALE * k.z;
            KT[(k0 + 3) * PAD + s] = SCALE * k.w;
            *reinterpret_cast<float4*>(Vt + s * PAD + k0) = v;
        }
        __syncthreads();
        // logits for (landmark i, keys j0..j0+15)
        float L[16];
#pragma unroll
        for (int u = 0; u < 16; u++) L[u] = 0.f;
        for (int k = 0; k < 64; k++) fma16(L, Qs[i * PAD + k], KT + k * PAD + j0);
        float e[16];
#pragma unroll
        for (int u = 0; u < 16; u++) { e[u] = __expf(L[u]); rsum += e[u]; }
        __syncthreads();               // all KT reads done
#pragma unroll
        for (int u = 0; u < 16; u++) KT[i * PAD + j0 + u] = e[u];   // E overlays KT
        __syncthreads();
        // PV: acc[d in j0..j0+15] += sum_s E[i][s] * V[s][d]
        for (int s = 0; s < 64; s++) fma16(acc, KT[i * PAD + s], Vt + s * PAD + j0);
        __syncthreads();
    }
#pragma unroll
    for (int u = 0; u < 16; u++)
        atomicAdd(&W2acc[(bh * 64 + i) * 64 + j0 + u], acc[u]);
    atomicAdd(&rowsum3[bh * 64 + i], rsum);
}

// ---------- E: W = inv(K2) @ (W2acc / rowsum3) ----------
__global__ __launch_bounds__(256) void wmid_kernel(const float* __restrict__ K2invg,
                                                   const float* __restrict__ W2acc,
                                                   const float* __restrict__ rowsum3,
                                                   float* __restrict__ Wg) {
    __shared__ float I1[64 * PAD], W2[64 * PAD];
    const int bh = blockIdx.x, t = threadIdx.x;
#pragma unroll
    for (int n = 0; n < 16; n++) {
        int f = t + n * 256;
        int r = f >> 6;
        I1[r * PAD + (f & 63)] = K2invg[bh * 4096 + f];
        W2[r * PAD + (f & 63)] = W2acc[bh * 4096 + f] / rowsum3[bh * 64 + r];
    }
    __syncthreads();
    const int i = t >> 2, j0 = (t & 3) * 16;
    float acc[16];
#pragma unroll
    for (int u = 0; u < 16; u++) acc[u] = 0.f;
    for (int k = 0; k < 64; k++) fma16(acc, I1[i * PAD + k], W2 + k * PAD + j0);
#pragma unroll
    for (int u = 0; u < 16; u++) Wg[bh * 4096 + i * 64 + j0 + u] = acc[u];
}

// ---------- F: X = softmax((SCALE*Q) Klm^T) @ W ----------
__global__ __launch_bounds__(256) void final_kernel(const float* __restrict__ Q,
                                                    const float* __restrict__ Klm,
                                                    const float* __restrict__ Wg,
                                                    float* __restrict__ out) {
    __shared__ float Qs[64 * PAD];   // doubles as P after logits
    __shared__ float KT[64 * PAD];
    __shared__ float Ws[64 * PAD];
    __shared__ float R[64 * 4];
    const int sc = blockIdx.x, bh = blockIdx.y, t = threadIdx.x;
    const int s0 = sc * 64;
    const float4* Q4 = reinterpret_cast<const float4*>(Q);
#pragma unroll
    for (int n = 0; n < 16; n++) {
        int f = t + n * 256;
        int r = f >> 6, k = f & 63;
        KT[k * PAD + r] = Klm[bh * 4096 + f];         // transposed
        Ws[r * PAD + k] = Wg[bh * 4096 + f];
    }
#pragma unroll
    for (int n = 0; n < 4; n++) {
        int f4 = t + n * 256;
        int r = f4 >> 4, k0 = (f4 & 15) * 4;
        int gidx4 = (bh * 4096 + s0 + r) * 16 + (f4 & 15);
        float4 q = Q4[gidx4];
        q.x *= SCALE; q.y *= SCALE; q.z *= SCALE; q.w *= SCALE;
        *reinterpret_cast<float4*>(Qs + r * PAD + k0) = q;
    }
    __syncthreads();
    const int i = t >> 2, q = t & 3, j0 = q * 16;
    float L[16];
#pragma unroll
    for (int u = 0; u < 16; u++) L[u] = 0.f;
    for (int k = 0; k < 64; k++) fma16(L, Qs[i * PAD + k], KT + k * PAD + j0);
    float e[16], ps = 0.f;
#pragma unroll
    for (int u = 0; u < 16; u++) { e[u] = __expf(L[u]); ps += e[u]; }
    R[i * 4 + q] = ps;
    __syncthreads();               // logits done -> Qs reusable
#pragma unroll
    for (int u = 0; u < 16; u++) Qs[i * PAD + j0 + u] = e[u];   // P overlays Qs
    __syncthreads();
    const float rs = R[i * 4 + 0] + R[i * 4 + 1] + R[i * 4 + 2] + R[i * 4 + 3];
    float acc[16];
#pragma unroll
    for (int u = 0; u < 16; u++) acc[u] = 0.f;
    for (int j = 0; j < 64; j++) fma16(acc, Qs[i * PAD + j], Ws + j * PAD + j0);
    const float inv = 1.0f / rs;
    float4* o4 = reinterpret_cast<float4*>(out + ((size_t)bh * 4096 + s0 + i) * 64 + j0);
#pragma unroll
    for (int u4 = 0; u4 < 4; u4++) {
        float4 o;
        o.x = acc[u4 * 4 + 0] * inv;
        o.y = acc[u4 * 4 + 1] * inv;
        o.z = acc[u4 * 4 + 2] * inv;
        o.w = acc[u4 * 4 + 3] * inv;
        o4[u4] = o;
    }
}

extern "C" void kernel_launch(void* const* d_in, const int* in_sizes, int n_in,
                              void* d_out, int out_size, void* d_ws, size_t ws_size,
                              hipStream_t stream) {
    const float* Q = (const float*)d_in[0];
    const float* K = (const float*)d_in[1];
    const float* V = (const float*)d_in[2];
    float* out = (float*)d_out;
    float* ws = (float*)d_ws;

    float* Qlm    = ws;                 // 64*64*64
    float* Klm    = ws + 262144;
    float* K2     = ws + 524288;
    float* K2inv  = ws + 786432;
    float* Wg     = ws + 1048576;
    float* W2acc  = ws + 1310720;       // zeroed
    float* rowsum3 = ws + 1572864;      // zeroed
    unsigned* colmax = (unsigned*)(ws + 1576960);  // zeroed

    hipMemsetAsync(W2acc, 0, (262144 + 4096 + 1) * sizeof(float), stream);

    pool_kernel<<<4096, 256, 0, stream>>>(Q, K, Qlm, Klm);
    k2_kernel<<<64, 256, 0, stream>>>(Qlm, Klm, K2, colmax);
    k3v_kernel<<<dim3(8, 64), 256, 0, stream>>>(Qlm, K, V, W2acc, rowsum3);
    inv_kernel<<<64, 256, 0, stream>>>(K2, colmax, K2inv);
    wmid_kernel<<<64, 256, 0, stream>>>(K2inv, W2acc, rowsum3, Wg);
    final_kernel<<<dim3(64, 64), 256, 0, stream>>>(Q, Klm, Wg, out);
}

// Round 3
// 370.003 us; speedup vs baseline: 1.5752x; 1.5752x over previous
//
#include <hip/hip_runtime.h>
#include <hip/hip_bf16.h>

#define PAD 68            // fp32 LDS pitch (small kernels)
#define KP  72            // bf16 LDS pitch: 144 B row -> 4-dword bank rotation, 2-way = free
#define SCALE 0.35355339059327379f

typedef __attribute__((ext_vector_type(8))) short bf16x8;
typedef __attribute__((ext_vector_type(4))) float f32x4;
#define MFMA_BF16 __builtin_amdgcn_mfma_f32_16x16x32_bf16

__device__ __forceinline__ short f2b(float f) {          // fp32 -> bf16 RNE
    unsigned u = __float_as_uint(f);
    u += 0x7fff + ((u >> 16) & 1);
    return (short)(u >> 16);
}
__device__ __forceinline__ float b2f(short h) {
    return __uint_as_float(((unsigned)(unsigned short)h) << 16);
}

__device__ __forceinline__ void fma16(float acc[16], float a, const float* b) {
    const float4* b4 = reinterpret_cast<const float4*>(b);
    float4 x0 = b4[0], x1 = b4[1], x2 = b4[2], x3 = b4[3];
    acc[0]  += a * x0.x; acc[1]  += a * x0.y; acc[2]  += a * x0.z; acc[3]  += a * x0.w;
    acc[4]  += a * x1.x; acc[5]  += a * x1.y; acc[6]  += a * x1.z; acc[7]  += a * x1.w;
    acc[8]  += a * x2.x; acc[9]  += a * x2.y; acc[10] += a * x2.z; acc[11] += a * x2.w;
    acc[12] += a * x3.x; acc[13] += a * x3.y; acc[14] += a * x3.z; acc[15] += a * x3.w;
}

// ---------- A: landmark pooling (Q,K -> Qlm,Klm, pre-scaled by SCALE/64) ----------
__global__ __launch_bounds__(256) void pool_kernel(const float* __restrict__ Q,
                                                   const float* __restrict__ K,
                                                   float* __restrict__ Qlm,
                                                   float* __restrict__ Klm) {
    __shared__ float4 red[256];
    const int blk = blockIdx.x;
    const int t = threadIdx.x;
    const int d4 = t & 15;
    const int rg = t >> 4;
    const float4* Q4 = reinterpret_cast<const float4*>(Q);
    const float4* K4 = reinterpret_cast<const float4*>(K);

    float4 sQ = {0.f, 0.f, 0.f, 0.f}, sK = {0.f, 0.f, 0.f, 0.f};
#pragma unroll
    for (int rr = 0; rr < 4; rr++) {
        int row = blk * 64 + rg * 4 + rr;
        int off4 = (row << 4) + d4;
        float4 q = Q4[off4], k = K4[off4];
        sQ.x += q.x; sQ.y += q.y; sQ.z += q.z; sQ.w += q.w;
        sK.x += k.x; sK.y += k.y; sK.z += k.z; sK.w += k.w;
    }
    const float c = SCALE * (1.0f / 64.0f);
    red[t] = sQ;
    __syncthreads();
    if (t < 16) {
        float4 s = {0.f, 0.f, 0.f, 0.f};
#pragma unroll
        for (int g = 0; g < 16; g++) {
            float4 v = red[g * 16 + t];
            s.x += v.x; s.y += v.y; s.z += v.z; s.w += v.w;
        }
        s.x *= c; s.y *= c; s.z *= c; s.w *= c;
        reinterpret_cast<float4*>(Qlm + blk * 64)[t] = s;
    }
    __syncthreads();
    red[t] = sK;
    __syncthreads();
    if (t < 16) {
        float4 s = {0.f, 0.f, 0.f, 0.f};
#pragma unroll
        for (int g = 0; g < 16; g++) {
            float4 v = red[g * 16 + t];
            s.x += v.x; s.y += v.y; s.z += v.z; s.w += v.w;
        }
        s.x *= c; s.y *= c; s.z *= c; s.w *= c;
        reinterpret_cast<float4*>(Klm + blk * 64)[t] = s;
    }
}

// ---------- B: K2 = softmax(Qlm Klm^T), global col-sum max ----------
__global__ __launch_bounds__(256) void k2_kernel(const float* __restrict__ Qlm,
                                                 const float* __restrict__ Klm,
                                                 float* __restrict__ K2g,
                                                 unsigned* __restrict__ colmax) {
    __shared__ float Ql[64 * PAD], Kl[64 * PAD], S2[64 * PAD];
    const int bh = blockIdx.x, t = threadIdx.x;
#pragma unroll
    for (int n = 0; n < 16; n++) {
        int f = t + n * 256;
        Ql[(f >> 6) * PAD + (f & 63)] = Qlm[bh * 4096 + f];
        Kl[(f >> 6) * PAD + (f & 63)] = Klm[bh * 4096 + f];
    }
    __syncthreads();
    const int i = t >> 2, j0 = (t & 3) * 16;
    float acc[16];
#pragma unroll
    for (int u = 0; u < 16; u++) acc[u] = 0.f;
    const float4* Ql4 = reinterpret_cast<const float4*>(Ql);
    const float4* Kl4 = reinterpret_cast<const float4*>(Kl);
    for (int k4 = 0; k4 < 16; k4++) {
        float4 a = Ql4[i * 17 + k4];
#pragma unroll
        for (int u = 0; u < 16; u++) {
            float4 b = Kl4[(j0 + u) * 17 + k4];
            acc[u] += a.x * b.x + a.y * b.y + a.z * b.z + a.w * b.w;
        }
    }
#pragma unroll
    for (int u = 0; u < 16; u++) S2[i * PAD + j0 + u] = acc[u];
    __syncthreads();
    if (t < 64) {
        float m = -1e30f;
        for (int j = 0; j < 64; j++) m = fmaxf(m, S2[t * PAD + j]);
        float sum = 0.f;
        for (int j = 0; j < 64; j++) {
            float e = __expf(S2[t * PAD + j] - m);
            S2[t * PAD + j] = e; sum += e;
        }
        float inv = 1.0f / sum;
        for (int j = 0; j < 64; j++) S2[t * PAD + j] *= inv;
    }
    __syncthreads();
#pragma unroll
    for (int n = 0; n < 16; n++) {
        int f = t + n * 256;
        K2g[bh * 4096 + f] = S2[(f >> 6) * PAD + (f & 63)];
    }
    if (t < 64) {
        float c = 0.f;
        for (int ii = 0; ii < 64; ii++) c += S2[ii * PAD + t];
        atomicMax(colmax, __float_as_uint(c));
    }
}

// ---------- C: Newton-Schulz inverse (6 iters) ----------
__global__ __launch_bounds__(256) void inv_kernel(const float* __restrict__ K2g,
                                                  const unsigned* __restrict__ colmax,
                                                  float* __restrict__ K2invg) {
    __shared__ float Vb[64 * PAD], Ab[64 * PAD], Tb[64 * PAD];
    const int bh = blockIdx.x, t = threadIdx.x;
    const float sc = 1.0f / __uint_as_float(*colmax);
    const float* Kg = K2g + bh * 4096;
#pragma unroll
    for (int n = 0; n < 16; n++) {
        int f = t + n * 256;
        Vb[(f >> 6) * PAD + (f & 63)] = sc * Kg[(f & 63) * 64 + (f >> 6)];
    }
    __syncthreads();
    const int i = t >> 2, j0 = (t & 3) * 16;
    for (int iter = 0; iter < 6; iter++) {
        float acc[16], vacc[16];
#pragma unroll
        for (int u = 0; u < 16; u++) acc[u] = 0.f;
        for (int k = 0; k < 64; k++) fma16(acc, Kg[i * 64 + k], Vb + k * PAD + j0);
#pragma unroll
        for (int u = 0; u < 16; u++) Ab[i * PAD + j0 + u] = acc[u];
        __syncthreads();
#pragma unroll
        for (int u = 0; u < 16; u++) acc[u] = 0.f;
        for (int k = 0; k < 64; k++) fma16(acc, Vb[i * PAD + k], Ab + k * PAD + j0);
#pragma unroll
        for (int u = 0; u < 16; u++) {
            vacc[u] = 13.f * Vb[i * PAD + j0 + u] - 15.f * acc[u];
            Tb[i * PAD + j0 + u] = acc[u];
        }
        __syncthreads();
#pragma unroll
        for (int u = 0; u < 16; u++) acc[u] = 0.f;
        for (int k = 0; k < 64; k++) fma16(acc, Tb[i * PAD + k], Ab + k * PAD + j0);
#pragma unroll
        for (int u = 0; u < 16; u++) { vacc[u] += 7.f * acc[u]; Vb[i * PAD + j0 + u] = acc[u]; }
        __syncthreads();
#pragma unroll
        for (int u = 0; u < 16; u++) acc[u] = 0.f;
        for (int k = 0; k < 64; k++) fma16(acc, Vb[i * PAD + k], Ab + k * PAD + j0);
#pragma unroll
        for (int u = 0; u < 16; u++) vacc[u] -= acc[u];
        __syncthreads();
#pragma unroll
        for (int u = 0; u < 16; u++) Vb[i * PAD + j0 + u] = 0.25f * vacc[u];
        __syncthreads();
    }
#pragma unroll
    for (int n = 0; n < 16; n++) {
        int f = t + n * 256;
        K2invg[bh * 4096 + f] = Vb[(f >> 6) * PAD + (f & 63)];
    }
}

// ---------- D (MFMA): W2acc += exp(Qlm (SCALE*K)^T) @ V ; rowsum3 += exp-sums ----------
__global__ __launch_bounds__(256) void k3v_mfma(const float* __restrict__ Qlm,
                                                const float* __restrict__ K,
                                                const float* __restrict__ V,
                                                float* __restrict__ W2acc,
                                                float* __restrict__ rowsum3) {
    __shared__ short Qs[64 * KP];   // A (matmul1): [landmark][dim]
    __shared__ short Kt[64 * KP];   // B (matmul1): [key][dim]
    __shared__ short Vt[64 * KP];   // B (matmul2): [dim][key]
    __shared__ short Eb[64 * KP];   // A (matmul2): [landmark][key]
    const int chunk = blockIdx.x, bh = blockIdx.y, t = threadIdx.x;
    const int w = t >> 6, lane = t & 63, quad = lane >> 4, l15 = lane & 15;
    const float4* Qlm4 = reinterpret_cast<const float4*>(Qlm);
    const float4* K4 = reinterpret_cast<const float4*>(K);
    const float4* V4 = reinterpret_cast<const float4*>(V);

    // stage Qlm (already SCALE/64-scaled by pool)
#pragma unroll
    for (int n = 0; n < 4; n++) {
        int f4 = t + n * 256;
        int r = f4 >> 4, dg = f4 & 15;
        float4 q = Qlm4[bh * 1024 + f4];
        ushort4 uq = { (unsigned short)f2b(q.x), (unsigned short)f2b(q.y),
                       (unsigned short)f2b(q.z), (unsigned short)f2b(q.w) };
        *reinterpret_cast<ushort4*>(&Qs[r * KP + dg * 4]) = uq;
    }

    f32x4 oacc[4];
    float rsum[4];
#pragma unroll
    for (int nt = 0; nt < 4; nt++) { oacc[nt] = (f32x4){0.f, 0.f, 0.f, 0.f}; rsum[nt] = 0.f; }

    for (int tile = 0; tile < 4; tile++) {
        const int sb = chunk * 256 + tile * 64;
        __syncthreads();   // protect Kt/Vt (prev matmuls) and Eb (prev matmul2)
        // stage K (scaled, row-major) and V (transposed)
#pragma unroll
        for (int n = 0; n < 4; n++) {
            int f4 = t + n * 256;
            int key = f4 >> 4, dg = f4 & 15;
            int g4 = (bh * 4096 + sb + key) * 16 + dg;
            float4 kk = K4[g4];
            ushort4 uk = { (unsigned short)f2b(SCALE * kk.x), (unsigned short)f2b(SCALE * kk.y),
                           (unsigned short)f2b(SCALE * kk.z), (unsigned short)f2b(SCALE * kk.w) };
            *reinterpret_cast<ushort4*>(&Kt[key * KP + dg * 4]) = uk;
            float4 vv = V4[g4];
            Vt[(dg * 4 + 0) * KP + key] = f2b(vv.x);
            Vt[(dg * 4 + 1) * KP + key] = f2b(vv.y);
            Vt[(dg * 4 + 2) * KP + key] = f2b(vv.z);
            Vt[(dg * 4 + 3) * KP + key] = f2b(vv.w);
        }
        __syncthreads();
        // matmul1: S[m=16w.., n=key] = Qlm . Kt^T
        bf16x8 a0 = *reinterpret_cast<const bf16x8*>(&Qs[(w * 16 + l15) * KP + quad * 8]);
        bf16x8 a1 = *reinterpret_cast<const bf16x8*>(&Qs[(w * 16 + l15) * KP + quad * 8 + 32]);
#pragma unroll
        for (int nt = 0; nt < 4; nt++) {
            bf16x8 b0 = *reinterpret_cast<const bf16x8*>(&Kt[(nt * 16 + l15) * KP + quad * 8]);
            bf16x8 b1 = *reinterpret_cast<const bf16x8*>(&Kt[(nt * 16 + l15) * KP + quad * 8 + 32]);
            f32x4 c = {0.f, 0.f, 0.f, 0.f};
            c = MFMA_BF16(a0, b0, c, 0, 0, 0);
            c = MFMA_BF16(a1, b1, c, 0, 0, 0);
#pragma unroll
            for (int reg = 0; reg < 4; reg++) {
                float e = __expf(c[reg]);
                rsum[reg] += e;
                Eb[(w * 16 + quad * 4 + reg) * KP + nt * 16 + l15] = f2b(e);
            }
        }
        // matmul2: oacc += E . Vt^T   (wave reads only its own E rows -> no barrier)
        bf16x8 e0 = *reinterpret_cast<const bf16x8*>(&Eb[(w * 16 + l15) * KP + quad * 8]);
        bf16x8 e1 = *reinterpret_cast<const bf16x8*>(&Eb[(w * 16 + l15) * KP + quad * 8 + 32]);
#pragma unroll
        for (int nt = 0; nt < 4; nt++) {
            bf16x8 b0 = *reinterpret_cast<const bf16x8*>(&Vt[(nt * 16 + l15) * KP + quad * 8]);
            bf16x8 b1 = *reinterpret_cast<const bf16x8*>(&Vt[(nt * 16 + l15) * KP + quad * 8 + 32]);
            oacc[nt] = MFMA_BF16(e0, b0, oacc[nt], 0, 0, 0);
            oacc[nt] = MFMA_BF16(e1, b1, oacc[nt], 0, 0, 0);
        }
    }
    // reduce rowsums over the 16 lanes of each quad
#pragma unroll
    for (int reg = 0; reg < 4; reg++) {
        float s = rsum[reg];
        s += __shfl_xor(s, 1); s += __shfl_xor(s, 2);
        s += __shfl_xor(s, 4); s += __shfl_xor(s, 8);
        rsum[reg] = s;
    }
    const int row0 = w * 16 + quad * 4;
    if (l15 == 0) {
#pragma unroll
        for (int reg = 0; reg < 4; reg++)
            atomicAdd(&rowsum3[bh * 64 + row0 + reg], rsum[reg]);
    }
#pragma unroll
    for (int nt = 0; nt < 4; nt++)
#pragma unroll
        for (int reg = 0; reg < 4; reg++)
            atomicAdd(&W2acc[(bh * 64 + row0 + reg) * 64 + nt * 16 + l15], oacc[nt][reg]);
}

// ---------- E: W = inv(K2) @ (W2acc / rowsum3) ----------
__global__ __launch_bounds__(256) void wmid_kernel(const float* __restrict__ K2invg,
                                                   const float* __restrict__ W2acc,
                                                   const float* __restrict__ rowsum3,
                                                   float* __restrict__ Wg) {
    __shared__ float I1[64 * PAD], W2[64 * PAD];
    const int bh = blockIdx.x, t = threadIdx.x;
#pragma unroll
    for (int n = 0; n < 16; n++) {
        int f = t + n * 256;
        int r = f >> 6;
        I1[r * PAD + (f & 63)] = K2invg[bh * 4096 + f];
        W2[r * PAD + (f & 63)] = W2acc[bh * 4096 + f] / rowsum3[bh * 64 + r];
    }
    __syncthreads();
    const int i = t >> 2, j0 = (t & 3) * 16;
    float acc[16];
#pragma unroll
    for (int u = 0; u < 16; u++) acc[u] = 0.f;
    for (int k = 0; k < 64; k++) fma16(acc, I1[i * PAD + k], W2 + k * PAD + j0);
#pragma unroll
    for (int u = 0; u < 16; u++) Wg[bh * 4096 + i * 64 + j0 + u] = acc[u];
}

// ---------- F (MFMA): X = softmax((SCALE*Q) Klm^T) @ W ----------
__global__ __launch_bounds__(256) void final_mfma(const float* __restrict__ Q,
                                                  const float* __restrict__ Klm,
                                                  const float* __restrict__ Wg,
                                                  float* __restrict__ out) {
    __shared__ short Qs[64 * KP];   // A (mm1): [seqrow][dim]
    __shared__ short Kl[64 * KP];   // B (mm1): [landmark][dim]
    __shared__ short Eb[64 * KP];   // A (mm2): [seqrow][landmark]
    __shared__ short Wh[64 * KP];   // B (mm2) hi: [dim][landmark]
    __shared__ short Wl[64 * KP];   // B (mm2) lo
    const int sc = blockIdx.x, bh = blockIdx.y, t = threadIdx.x;
    const int w = t >> 6, lane = t & 63, quad = lane >> 4, l15 = lane & 15;
    const int s0 = sc * 64;
    const float4* Q4 = reinterpret_cast<const float4*>(Q);
    const float4* Klm4 = reinterpret_cast<const float4*>(Klm);
    const float4* W4 = reinterpret_cast<const float4*>(Wg);

#pragma unroll
    for (int n = 0; n < 4; n++) {
        int f4 = t + n * 256;
        int r = f4 >> 4, dg = f4 & 15;
        // Klm row-major (already scaled)
        float4 kl = Klm4[bh * 1024 + f4];
        ushort4 uk = { (unsigned short)f2b(kl.x), (unsigned short)f2b(kl.y),
                       (unsigned short)f2b(kl.z), (unsigned short)f2b(kl.w) };
        *reinterpret_cast<ushort4*>(&Kl[r * KP + dg * 4]) = uk;
        // Q tile, scaled
        float4 q = Q4[(bh * 4096 + s0 + r) * 16 + dg];
        ushort4 uq = { (unsigned short)f2b(SCALE * q.x), (unsigned short)f2b(SCALE * q.y),
                       (unsigned short)f2b(SCALE * q.z), (unsigned short)f2b(SCALE * q.w) };
        *reinterpret_cast<ushort4*>(&Qs[r * KP + dg * 4]) = uq;
        // W split hi/lo, transposed: Wh[dim][landmark]
        float4 ww = W4[bh * 1024 + f4];     // W[r=landmark][dg*4..]
        float wv[4] = {ww.x, ww.y, ww.z, ww.w};
#pragma unroll
        for (int i = 0; i < 4; i++) {
            short hi = f2b(wv[i]);
            Wh[(dg * 4 + i) * KP + r] = hi;
            Wl[(dg * 4 + i) * KP + r] = f2b(wv[i] - b2f(hi));
        }
    }
    __syncthreads();
    // mm1: S = Qs . Kl^T ; exp ; rowsum ; Eb
    bf16x8 a0 = *reinterpret_cast<const bf16x8*>(&Qs[(w * 16 + l15) * KP + quad * 8]);
    bf16x8 a1 = *reinterpret_cast<const bf16x8*>(&Qs[(w * 16 + l15) * KP + quad * 8 + 32]);
    float rsum[4] = {0.f, 0.f, 0.f, 0.f};
#pragma unroll
    for (int nt = 0; nt < 4; nt++) {
        bf16x8 b0 = *reinterpret_cast<const bf16x8*>(&Kl[(nt * 16 + l15) * KP + quad * 8]);
        bf16x8 b1 = *reinterpret_cast<const bf16x8*>(&Kl[(nt * 16 + l15) * KP + quad * 8 + 32]);
        f32x4 c = {0.f, 0.f, 0.f, 0.f};
        c = MFMA_BF16(a0, b0, c, 0, 0, 0);
        c = MFMA_BF16(a1, b1, c, 0, 0, 0);
#pragma unroll
        for (int reg = 0; reg < 4; reg++) {
            float e = __expf(c[reg]);
            rsum[reg] += e;
            Eb[(w * 16 + quad * 4 + reg) * KP + nt * 16 + l15] = f2b(e);
        }
    }
#pragma unroll
    for (int reg = 0; reg < 4; reg++) {
        float s = rsum[reg];
        s += __shfl_xor(s, 1); s += __shfl_xor(s, 2);
        s += __shfl_xor(s, 4); s += __shfl_xor(s, 8);
        rsum[reg] = 1.0f / s;
    }
    // mm2: X = Eb . (Wh + Wl)   (wave reads only its own Eb rows -> no barrier needed)
    bf16x8 e0 = *reinterpret_cast<const bf16x8*>(&Eb[(w * 16 + l15) * KP + quad * 8]);
    bf16x8 e1 = *reinterpret_cast<const bf16x8*>(&Eb[(w * 16 + l15) * KP + quad * 8 + 32]);
    const int row0 = w * 16 + quad * 4;
#pragma unroll
    for (int nt = 0; nt < 4; nt++) {
        bf16x8 bh0 = *reinterpret_cast<const bf16x8*>(&Wh[(nt * 16 + l15) * KP + quad * 8]);
        bf16x8 bh1 = *reinterpret_cast<const bf16x8*>(&Wh[(nt * 16 + l15) * KP + quad * 8 + 32]);
        bf16x8 bl0 = *reinterpret_cast<const bf16x8*>(&Wl[(nt * 16 + l15) * KP + quad * 8]);
        bf16x8 bl1 = *reinterpret_cast<const bf16x8*>(&Wl[(nt * 16 + l15) * KP + quad * 8 + 32]);
        f32x4 c = {0.f, 0.f, 0.f, 0.f};
        c = MFMA_BF16(e0, bh0, c, 0, 0, 0);
        c = MFMA_BF16(e1, bh1, c, 0, 0, 0);
        c = MFMA_BF16(e0, bl0, c, 0, 0, 0);
        c = MFMA_BF16(e1, bl1, c, 0, 0, 0);
#pragma unroll
        for (int reg = 0; reg < 4; reg++)
            out[((size_t)bh * 4096 + s0 + row0 + reg) * 64 + nt * 16 + l15] = c[reg] * rsum[reg];
    }
}

extern "C" void kernel_launch(void* const* d_in, const int* in_sizes, int n_in,
                              void* d_out, int out_size, void* d_ws, size_t ws_size,
                              hipStream_t stream) {
    const float* Q = (const float*)d_in[0];
    const float* K = (const float*)d_in[1];
    const float* V = (const float*)d_in[2];
    float* out = (float*)d_out;
    float* ws = (float*)d_ws;

    float* Qlm    = ws;
    float* Klm    = ws + 262144;
    float* K2     = ws + 524288;
    float* K2inv  = ws + 786432;
    float* Wg     = ws + 1048576;
    float* W2acc  = ws + 1310720;       // zeroed
    float* rowsum3 = ws + 1572864;      // zeroed
    unsigned* colmax = (unsigned*)(ws + 1576960);  // zeroed

    hipMemsetAsync(W2acc, 0, (262144 + 4096 + 1) * sizeof(float), stream);

    pool_kernel<<<4096, 256, 0, stream>>>(Q, K, Qlm, Klm);
    k2_kernel<<<64, 256, 0, stream>>>(Qlm, Klm, K2, colmax);
    k3v_mfma<<<dim3(16, 64), 256, 0, stream>>>(Qlm, K, V, W2acc, rowsum3);
    inv_kernel<<<64, 256, 0, stream>>>(K2, colmax, K2inv);
    wmid_kernel<<<64, 256, 0, stream>>>(K2inv, W2acc, rowsum3, Wg);
    final_mfma<<<dim3(64, 64), 256, 0, stream>>>(Q, Klm, Wg, out);
}